// Round 1
// baseline (286.852 us; speedup 1.0000x reference)
//
#include <hip/hip_runtime.h>
#include <math.h>

#define NN 32768
#define BB 16
#define LL 2048
#define NE (NN*9)
#define EPSF 1e-6f

// ---- output layout (flat float32, reference tuple order) ----
#define O_NODEPOS 0
#define O_DISNODE (NN*16)
#define O_ANGNODE (O_DISNODE + NN*48)
#define O_DIRNODE (O_ANGNODE + NN*12)
#define O_EIDX    (O_DIRNODE + NN*9)
#define O_CTX     (O_EIDX + 2*NE)
#define O_INTER   (O_CTX + NE)
#define O_EDGEPOS (O_INTER + NE)
#define O_DISEDGE (O_EDGEPOS + NE*16)
#define O_ANGEDGE (O_DISEDGE + NE*64)
#define O_DIREDGE (O_ANGEDGE + NE*4)

struct F3 { float x, y, z; };
__device__ __forceinline__ F3 mkf3(float x, float y, float z){ F3 r; r.x=x; r.y=y; r.z=z; return r; }
__device__ __forceinline__ F3 subf3(F3 a, F3 b){ return mkf3(a.x-b.x, a.y-b.y, a.z-b.z); }
__device__ __forceinline__ float dotf3(F3 a, F3 b){ return a.x*b.x + a.y*b.y + a.z*b.z; }
__device__ __forceinline__ F3 crossf3(F3 a, F3 b){
  return mkf3(a.y*b.z - a.z*b.y, a.z*b.x - a.x*b.z, a.x*b.y - a.y*b.x);
}
__device__ __forceinline__ F3 normf3(F3 v){
  float n = sqrtf(v.x*v.x + v.y*v.y + v.z*v.z);
  float m = fmaxf(n, 1e-12f);
  return mkf3(v.x/m, v.y/m, v.z/m);
}
__device__ __forceinline__ float sgnf(float x){ return (x > 0.f) ? 1.f : ((x < 0.f) ? -1.f : 0.f); }
__device__ __forceinline__ float clampf(float x, float lo, float hi){ return fminf(fmaxf(x, lo), hi); }

__device__ __forceinline__ F3 ldatom(const float* __restrict__ X, int n, int a){
  const float* p = X + (size_t)n*12 + a*3;
  return mkf3(p[0], p[1], p[2]);
}
__device__ __forceinline__ float dist_eps(F3 a, F3 b){
  F3 d = subf3(a, b);
  return sqrtf(dotf3(d, d) + EPSF);
}
// freq[t] = 10000^(-t/8), t=0..7 (pos-embed frequencies)
__device__ __forceinline__ float frq(int t){
  const float F[8] = {1.0f, 0.31622776601683794f, 0.1f, 0.031622776601683794f,
                      0.01f, 0.0031622776601683794f, 0.001f, 0.00031622776601683794f};
  return F[t];
}
__device__ __forceinline__ void rbf16(float* __restrict__ dst, float d){
  #pragma unroll
  for (int t = 0; t < 16; ++t){
    float mu = (float)t * (20.0f/15.0f);
    float z = (d - mu) * (1.0f/1.25f);
    dst[t] = __expf(-z*z);
  }
}
// O frame for node n (zero if padded/masked). Rows O0,O1,O2 are o1, nf, o1 x nf.
__device__ __forceinline__ void computeO(const float* __restrict__ X, int n, F3& O0, F3& O1, F3& O2){
  int l = n & (LL-1);
  int b = n >> 11;
  bool fm = !((l <= 1) || ((l >= LL-2) && (b < BB-1)));
  bool has = fm && (n >= 1) && (n <= NN-3);
  if (has){
    F3 cm = ldatom(X, n-1, 1), c0 = ldatom(X, n, 1), cp = ldatom(X, n+1, 1);
    F3 uc2 = normf3(subf3(c0, cm));
    F3 uc1 = normf3(subf3(cp, c0));
    F3 nf  = normf3(crossf3(uc2, uc1));
    F3 o1  = normf3(subf3(uc2, uc1));
    O0 = o1; O1 = nf; O2 = crossf3(o1, nf);
  } else {
    O0 = mkf3(0,0,0); O1 = mkf3(0,0,0); O2 = mkf3(0,0,0);
  }
}

// ================= kernel 1: per-batch top-9 nearest neighbors =================
// 8 lanes per row, 256 candidates per lane; u64 key = (s_bits<<32)|j gives exact
// (distance asc, index asc) ordering; shfl-based 8-way merge of sorted lists.
__global__ __launch_bounds__(256) void topk_kernel(const float* __restrict__ X,
                                                   float* __restrict__ out){
  __shared__ float4 sca[LL + (LL >> 8)];           // skewed: idx = p + (p>>8) (bank de-conflict)
  __shared__ unsigned long long skeys[32][8][9];
  const int tid = threadIdx.x;
  const int block0 = blockIdx.x * 32;              // first global row of this block
  const int b = block0 >> 11;
  const int base = b << 11;

  for (int p = tid; p < LL; p += 256){
    const float* xp = X + (size_t)(base + p)*12 + 3;   // CA atom
    sca[p + (p >> 8)] = make_float4(xp[0], xp[1], xp[2], 0.f);
  }
  __syncthreads();

  const int r = tid >> 3;          // row within block (0..31)
  const int k = tid & 7;           // lane group within row
  const int n = block0 + r;        // global row node
  const int il = n - base;         // local row index
  const float4 ci = sca[il + (il >> 8)];

  unsigned long long kk[9];
  #pragma unroll
  for (int t = 0; t < 9; ++t) kk[t] = ~0ull;

  const int j0 = k << 8;
  #pragma unroll 4
  for (int jj = 0; jj < 256; ++jj){
    const int j = j0 + jj;
    const float4 cj = sca[j + k];  // (j>>8)==k
    const float dx = ci.x - cj.x, dy = ci.y - cj.y, dz = ci.z - cj.z;
    const float s = dx*dx + dy*dy + dz*dz;
    unsigned long long key = ((unsigned long long)__float_as_uint(s) << 32) | (unsigned)j;
    #pragma unroll
    for (int t = 0; t < 9; ++t){
      const bool lt = key < kk[t];
      const unsigned long long mn = lt ? key : kk[t];
      const unsigned long long mx = lt ? kk[t] : key;
      kk[t] = mn; key = mx;
    }
  }
  #pragma unroll
  for (int t = 0; t < 9; ++t) skeys[r][k][t] = kk[t];
  __syncthreads();

  // merge 8 sorted 9-lists -> global top-9 (keys unique, so winner is unique)
  int ptr = 0;
  int cols[9];
  #pragma unroll
  for (int t = 0; t < 9; ++t){
    unsigned long long h = skeys[r][k][ptr];
    unsigned long long m = h;
    unsigned long long o;
    o = (unsigned long long)__shfl_xor((long long)m, 1, 8); if (o < m) m = o;
    o = (unsigned long long)__shfl_xor((long long)m, 2, 8); if (o < m) m = o;
    o = (unsigned long long)__shfl_xor((long long)m, 4, 8); if (o < m) m = o;
    ptr += (h == m) ? 1 : 0;
    cols[t] = (int)(unsigned)m;    // low 32 bits = local col index
  }
  if (k == 0){
    const int be = n * 9;
    #pragma unroll
    for (int t = 0; t < 9; ++t){
      out[O_EIDX + be + t] = (float)n;
      out[O_EIDX + NE + be + t] = (float)(base + cols[t]);
    }
  }
}

// ================= kernel 2: node features =================
__global__ __launch_bounds__(256) void node_kernel(const float* __restrict__ X,
                                                   float* __restrict__ out){
  const int n = blockIdx.x * 256 + threadIdx.x;
  if (n >= NN) return;
  const int l = n & (LL-1);
  const int b = n >> 11;

  // ---- node_pos ----
  {
    const float p = (float)l;
    #pragma unroll
    for (int t = 0; t < 8; ++t){
      float sv, cv;
      sincosf(p * frq(t), &sv, &cv);
      out[O_NODEPOS + n*16 + t] = cv;
      out[O_NODEPOS + n*16 + 8 + t] = sv;
    }
  }

  // ---- dis_node ----
  const F3 x0 = ldatom(X,n,0), x1 = ldatom(X,n,1), x2 = ldatom(X,n,2), x3 = ldatom(X,n,3);
  {
    float buf[16];
    rbf16(buf, dist_eps(x0, x1));
    #pragma unroll
    for (int t=0;t<16;++t) out[O_DISNODE + n*48 + t] = buf[t];
    rbf16(buf, dist_eps(x2, x1));
    #pragma unroll
    for (int t=0;t<16;++t) out[O_DISNODE + n*48 + 16 + t] = buf[t];
    rbf16(buf, dist_eps(x3, x1));
    #pragma unroll
    for (int t=0;t<16;++t) out[O_DISNODE + n*48 + 32 + t] = buf[t];
  }

  // ---- angle_node ----
  {
    const bool am = !((l <= 1) || ((l == LL-1) && (b < BB-1)));
    const float amf = am ? 1.f : 0.f;
    const int t0 = 3*n - 1;
    F3 P[6];
    #pragma unroll
    for (int q = 0; q < 6; ++q){
      int t = t0 + q;
      t = t < 0 ? 0 : (t > 3*NN - 1 ? 3*NN - 1 : t);
      const int nn2 = t / 3, aa = t - nn2*3;
      P[q] = ldatom(X, nn2, aa);
    }
    F3 U[5];
    #pragma unroll
    for (int q = 0; q < 5; ++q) U[q] = normf3(subf3(P[q+1], P[q]));
    #pragma unroll
    for (int cc = 0; cc < 3; ++cc){
      const int m = 3*n + cc - 1;
      float cD = 1.f, sD = 0.f, cA = 1.f, sA = 0.f;   // pad -> Dih=Ang=0
      if (m >= 0 && m <= 3*NN - 4){
        const F3 u2 = U[cc], u1 = U[cc+1], u0 = U[cc+2];
        const F3 n2 = normf3(crossf3(u2, u1));
        const F3 n1 = normf3(crossf3(u1, u0));
        const float cd_ = clampf(dotf3(n2, n1), -1.f + EPSF, 1.f - EPSF);
        const float sg = sgnf(dotf3(u2, n1));
        cD = cd_;                                        // cos(sign*acos(c)) = c
        sD = sg * sqrtf(fmaxf(1.f - cd_*cd_, 0.f));      // sin(sign*acos(c)) = sign*sqrt(1-c^2)
        const float ca_ = clampf(dotf3(u2, u1), -1.f + EPSF, 1.f - EPSF);
        cA = ca_;
        sA = sqrtf(fmaxf(1.f - ca_*ca_, 0.f));
      }
      out[O_ANGNODE + n*12 + cc]     = cD * amf;
      out[O_ANGNODE + n*12 + 3 + cc] = sD * amf;
      out[O_ANGNODE + n*12 + 6 + cc] = cA * amf;
      out[O_ANGNODE + n*12 + 9 + cc] = sA * amf;
    }
  }

  // ---- direct_node ----
  {
    F3 O0, O1, O2;
    computeO(X, n, O0, O1, O2);
    const F3 vs[3] = { subf3(x0, x1), subf3(x2, x1), subf3(x3, x1) };
    #pragma unroll
    for (int ai = 0; ai < 3; ++ai){
      F3 w = mkf3(dotf3(O0, vs[ai]), dotf3(O1, vs[ai]), dotf3(O2, vs[ai]));
      w = normf3(w);
      out[O_DIRNODE + n*9 + ai*3 + 0] = w.x;
      out[O_DIRNODE + n*9 + ai*3 + 1] = w.y;
      out[O_DIRNODE + n*9 + ai*3 + 2] = w.z;
    }
  }
}

// ================= kernel 3: edge features =================
__global__ __launch_bounds__(256) void edge_kernel(const float* __restrict__ X,
                                                   const int* __restrict__ seg,
                                                   float* __restrict__ out){
  const int e = blockIdx.x * 256 + threadIdx.x;
  if (e >= NE) return;
  const int n = e / 9;
  const int c = (int)out[O_EIDX + NE + e];   // col written by topk_kernel (same stream)

  // masks
  const float ctx = (seg[n] == seg[c]) ? 1.f : 0.f;
  out[O_CTX + e] = ctx;
  out[O_INTER + e] = 1.f - ctx;

  // edge_pos
  {
    const float p = (float)(n - c);
    #pragma unroll
    for (int t = 0; t < 8; ++t){
      float sv, cv;
      sincosf(p * frq(t), &sv, &cv);
      out[O_EDGEPOS + e*16 + t] = cv;
      out[O_EDGEPOS + e*16 + 8 + t] = sv;
    }
  }

  // dis_edge
  const F3 xc1 = ldatom(X, c, 1);
  {
    float buf[16];
    #pragma unroll
    for (int a = 0; a < 4; ++a){
      const F3 xr = ldatom(X, n, a);
      rbf16(buf, dist_eps(xr, xc1));
      #pragma unroll
      for (int t = 0; t < 16; ++t) out[O_DISEDGE + e*64 + a*16 + t] = buf[t];
    }
  }

  // angle_edge (quaternion of R = Or^T * Oc)
  F3 Ar0, Ar1, Ar2, Ac0, Ac1, Ac2;
  computeO(X, n, Ar0, Ar1, Ar2);
  computeO(X, c, Ac0, Ac1, Ac2);
  {
    const float R00 = Ar0.x*Ac0.x + Ar1.x*Ac1.x + Ar2.x*Ac2.x;
    const float R01 = Ar0.x*Ac0.y + Ar1.x*Ac1.y + Ar2.x*Ac2.y;
    const float R02 = Ar0.x*Ac0.z + Ar1.x*Ac1.z + Ar2.x*Ac2.z;
    const float R10 = Ar0.y*Ac0.x + Ar1.y*Ac1.x + Ar2.y*Ac2.x;
    const float R11 = Ar0.y*Ac0.y + Ar1.y*Ac1.y + Ar2.y*Ac2.y;
    const float R12 = Ar0.y*Ac0.z + Ar1.y*Ac1.z + Ar2.y*Ac2.z;
    const float R20 = Ar0.z*Ac0.x + Ar1.z*Ac1.x + Ar2.z*Ac2.x;
    const float R21 = Ar0.z*Ac0.y + Ar1.z*Ac1.y + Ar2.z*Ac2.y;
    const float R22 = Ar0.z*Ac0.z + Ar1.z*Ac1.z + Ar2.z*Ac2.z;
    const float m0 = 0.5f * sqrtf(fabsf(1.f + R00 - R11 - R22) + 1e-12f);
    const float m1 = 0.5f * sqrtf(fabsf(1.f - R00 + R11 - R22) + 1e-12f);
    const float m2 = 0.5f * sqrtf(fabsf(1.f - R00 - R11 + R22) + 1e-12f);
    const float qx = sgnf(R21 - R12) * m0;
    const float qy = sgnf(R02 - R20) * m1;
    const float qz = sgnf(R10 - R01) * m2;
    const float qw = sqrtf(fmaxf(1.f + R00 + R11 + R22, 0.f) + 1e-12f) * 0.5f;
    const float qn = fmaxf(sqrtf(qx*qx + qy*qy + qz*qz + qw*qw), 1e-12f);
    out[O_ANGEDGE + e*4 + 0] = qx / qn;
    out[O_ANGEDGE + e*4 + 1] = qy / qn;
    out[O_ANGEDGE + e*4 + 2] = qz / qn;
    out[O_ANGEDGE + e*4 + 3] = qw / qn;
  }

  // direct_edge: atoms {0,2,3} of row node, in col frame
  {
    const int atoms[3] = {0, 2, 3};
    #pragma unroll
    for (int ai = 0; ai < 3; ++ai){
      const F3 xr = ldatom(X, n, atoms[ai]);
      const F3 v = subf3(xr, xc1);
      F3 w = mkf3(dotf3(Ac0, v), dotf3(Ac1, v), dotf3(Ac2, v));
      w = normf3(w);
      out[O_DIREDGE + e*9 + ai*3 + 0] = w.x;
      out[O_DIREDGE + e*9 + ai*3 + 1] = w.y;
      out[O_DIREDGE + e*9 + ai*3 + 2] = w.z;
    }
  }
}

extern "C" void kernel_launch(void* const* d_in, const int* in_sizes, int n_in,
                              void* d_out, int out_size, void* d_ws, size_t ws_size,
                              hipStream_t stream) {
  const float* X = (const float*)d_in[0];
  const int* seg = (const int*)d_in[1];
  float* out = (float*)d_out;
  topk_kernel<<<NN/32, 256, 0, stream>>>(X, out);                 // writes edge_index
  node_kernel<<<NN/256, 256, 0, stream>>>(X, out);                // node features
  edge_kernel<<<(NE + 255)/256, 256, 0, stream>>>(X, seg, out);   // edge features (reads edge_index)
}

// Round 2
// 271.338 us; speedup vs baseline: 1.0572x; 1.0572x over previous
//
#include <hip/hip_runtime.h>
#include <math.h>

#define NN 32768
#define BB 16
#define LL 2048
#define NE (NN*9)
#define EPSF 1e-6f
#define CAP 32

// ---- output layout (flat float32, reference tuple order) ----
#define O_NODEPOS 0
#define O_DISNODE (NN*16)
#define O_ANGNODE (O_DISNODE + NN*48)
#define O_DIRNODE (O_ANGNODE + NN*12)
#define O_EIDX    (O_DIRNODE + NN*9)
#define O_CTX     (O_EIDX + 2*NE)
#define O_INTER   (O_CTX + NE)
#define O_EDGEPOS (O_INTER + NE)
#define O_DISEDGE (O_EDGEPOS + NE*16)
#define O_ANGEDGE (O_DISEDGE + NE*64)
#define O_DIREDGE (O_ANGEDGE + NE*4)

struct F3 { float x, y, z; };
__device__ __forceinline__ F3 mkf3(float x, float y, float z){ F3 r; r.x=x; r.y=y; r.z=z; return r; }
__device__ __forceinline__ F3 subf3(F3 a, F3 b){ return mkf3(a.x-b.x, a.y-b.y, a.z-b.z); }
__device__ __forceinline__ float dotf3(F3 a, F3 b){ return a.x*b.x + a.y*b.y + a.z*b.z; }
__device__ __forceinline__ F3 crossf3(F3 a, F3 b){
  return mkf3(a.y*b.z - a.z*b.y, a.z*b.x - a.x*b.z, a.x*b.y - a.y*b.x);
}
__device__ __forceinline__ F3 normf3(F3 v){
  float n = sqrtf(v.x*v.x + v.y*v.y + v.z*v.z);
  float m = fmaxf(n, 1e-12f);
  return mkf3(v.x/m, v.y/m, v.z/m);
}
__device__ __forceinline__ float sgnf(float x){ return (x > 0.f) ? 1.f : ((x < 0.f) ? -1.f : 0.f); }
__device__ __forceinline__ float clampf(float x, float lo, float hi){ return fminf(fmaxf(x, lo), hi); }

__device__ __forceinline__ F3 ldatom(const float* __restrict__ X, int n, int a){
  const float* p = X + (size_t)n*12 + a*3;
  return mkf3(p[0], p[1], p[2]);
}
__device__ __forceinline__ float dist_eps(F3 a, F3 b){
  F3 d = subf3(a, b);
  return sqrtf(dotf3(d, d) + EPSF);
}
// freq[t] = 10000^(-t/8), t=0..7
__device__ __forceinline__ float frq(int t){
  const float F[8] = {1.0f, 0.31622776601683794f, 0.1f, 0.031622776601683794f,
                      0.01f, 0.0031622776601683794f, 0.001f, 0.00031622776601683794f};
  return F[t];
}
__device__ __forceinline__ float frq_dyn(int t){   // branch-free: 2^(t * -log2(10000)/8)
  return exp2f((float)t * -1.6609640474436813f);
}
__device__ __forceinline__ void rbf16(float* __restrict__ dst, float d){
  #pragma unroll
  for (int t = 0; t < 16; ++t){
    float mu = (float)t * (20.0f/15.0f);
    float z = (d - mu) * (1.0f/1.25f);
    dst[t] = __expf(-z*z);
  }
}
// O frame for node n (zero if padded/masked). Rows O0,O1,O2 = o1, nf, o1 x nf.
__device__ __forceinline__ void computeO(const float* __restrict__ X, int n, F3& O0, F3& O1, F3& O2){
  int l = n & (LL-1);
  int b = n >> 11;
  bool fm = !((l <= 1) || ((l >= LL-2) && (b < BB-1)));
  bool has = fm && (n >= 1) && (n <= NN-3);
  if (has){
    F3 cm = ldatom(X, n-1, 1), c0 = ldatom(X, n, 1), cp = ldatom(X, n+1, 1);
    F3 uc2 = normf3(subf3(c0, cm));
    F3 uc1 = normf3(subf3(cp, c0));
    F3 nf  = normf3(crossf3(uc2, uc1));
    F3 o1  = normf3(subf3(uc2, uc1));
    O0 = o1; O1 = nf; O2 = crossf3(o1, nf);
  } else {
    O0 = mkf3(0,0,0); O1 = mkf3(0,0,0); O2 = mkf3(0,0,0);
  }
}

// ================= kernel 1: per-batch top-9 nearest neighbors =================
// Pass 1: per-lane top-9 VALUES via f32 min/max chains (2 instr/slot).
// Merge: 8-lane pointer-merge of sorted lists -> threshold t9 >= true 9th value.
// Pass 2: rescan, collect (s,idx) with s <= t9 into LDS; exact (s,idx)-lex top-9.
__global__ __launch_bounds__(256) void topk_kernel(const float* __restrict__ X,
                                                   float* __restrict__ out){
  __shared__ float4 sca[LL + (LL >> 8)];          // skewed stage of batch CA coords
  __shared__ unsigned long long ebuf[32][CAP];
  __shared__ int ecnt[32];
  const int tid = threadIdx.x;
  const int block0 = blockIdx.x * 32;
  const int base = (block0 >> 11) << 11;

  if (tid < 32) ecnt[tid] = 0;
  for (int p = tid; p < LL; p += 256){
    const float* xp = X + (size_t)(base + p)*12 + 3;   // CA atom
    sca[p + (p >> 8)] = make_float4(xp[0], xp[1], xp[2], 0.f);
  }
  __syncthreads();

  const int r = tid >> 3;          // row within block (0..31)
  const int k = tid & 7;           // lane group within row
  const int n = block0 + r;
  const int il = n - base;
  const float4 ci = sca[il + (il >> 8)];
  const float4* __restrict__ basep = &sca[(k << 8) + k];  // this lane's 256 contiguous float4s

  float v[9];
  #pragma unroll
  for (int t = 0; t < 9; ++t) v[t] = __builtin_inff();

  #pragma unroll 8
  for (int jj = 0; jj < 256; ++jj){
    const float4 cj = basep[jj];
    const float dx = ci.x - cj.x, dy = ci.y - cj.y, dz = ci.z - cj.z;
    float key = fmaf(dz, dz, fmaf(dy, dy, dx*dx));
    #pragma unroll
    for (int t = 0; t < 9; ++t){
      const float mn = fminf(key, v[t]);
      key = fmaxf(key, v[t]);
      v[t] = mn;
    }
  }

  // 8-lane merge of sorted 9-lists -> t9 (9th smallest, duplicates-across-lanes collapsed
  // which only loosens the threshold). Pop-by-shift avoids dynamic register indexing.
  float t9 = 0.f;
  #pragma unroll
  for (int t = 0; t < 9; ++t){
    const float h = v[0];
    float m = h;
    m = fminf(m, __shfl_xor(m, 1, 8));
    m = fminf(m, __shfl_xor(m, 2, 8));
    m = fminf(m, __shfl_xor(m, 4, 8));
    const bool pop = (h == m);
    #pragma unroll
    for (int q = 0; q < 8; ++q) v[q] = pop ? v[q+1] : v[q];
    v[8] = pop ? __builtin_inff() : v[8];
    t9 = m;
  }

  // rescan: exact (s,idx) for everything at or below the threshold
  #pragma unroll 4
  for (int jj = 0; jj < 256; ++jj){
    const float4 cj = basep[jj];
    const float dx = ci.x - cj.x, dy = ci.y - cj.y, dz = ci.z - cj.z;
    const float s = fmaf(dz, dz, fmaf(dy, dy, dx*dx));   // bit-identical to pass 1
    if (s <= t9){
      const int slot = atomicAdd(&ecnt[r], 1);
      if (slot < CAP)
        ebuf[r][slot] = ((unsigned long long)__float_as_uint(s) << 32) | (unsigned)((k << 8) + jj);
    }
  }
  __syncthreads();

  if (k == 0){
    const int m = min(ecnt[r], CAP);
    unsigned long long kk[9];
    #pragma unroll
    for (int t = 0; t < 9; ++t) kk[t] = ~0ull;
    for (int j = 0; j < m; ++j){
      unsigned long long key = ebuf[r][j];
      #pragma unroll
      for (int t = 0; t < 9; ++t){
        const bool lt = key < kk[t];
        const unsigned long long mn = lt ? key : kk[t];
        const unsigned long long mx = lt ? kk[t] : key;
        kk[t] = mn; key = mx;
      }
    }
    const int be = n * 9;
    #pragma unroll
    for (int t = 0; t < 9; ++t){
      out[O_EIDX + be + t] = (float)n;
      out[O_EIDX + NE + be + t] = (float)(base + (int)(unsigned)kk[t]);
    }
  }
}

// ================= kernel 1b: precompute O frames into ws =================
__global__ __launch_bounds__(256) void frames_kernel(const float* __restrict__ X,
                                                     float* __restrict__ ws){
  const int n = blockIdx.x * 256 + threadIdx.x;
  if (n >= NN) return;
  F3 O0, O1, O2;
  computeO(X, n, O0, O1, O2);
  float4* W = (float4*)ws;
  W[n*3 + 0] = make_float4(O0.x, O0.y, O0.z, 0.f);
  W[n*3 + 1] = make_float4(O1.x, O1.y, O1.z, 0.f);
  W[n*3 + 2] = make_float4(O2.x, O2.y, O2.z, 0.f);
}

// ================= kernel 2: node features =================
__global__ __launch_bounds__(256) void node_kernel(const float* __restrict__ X,
                                                   const float* __restrict__ ws,
                                                   float* __restrict__ out){
  const int n = blockIdx.x * 256 + threadIdx.x;
  if (n >= NN) return;
  const int l = n & (LL-1);
  const int b = n >> 11;

  // ---- node_pos ----
  {
    const float p = (float)l;
    #pragma unroll
    for (int t = 0; t < 8; ++t){
      float sv, cv;
      sincosf(p * frq(t), &sv, &cv);
      out[O_NODEPOS + n*16 + t] = cv;
      out[O_NODEPOS + n*16 + 8 + t] = sv;
    }
  }

  // ---- dis_node ----
  const F3 x0 = ldatom(X,n,0), x1 = ldatom(X,n,1), x2 = ldatom(X,n,2), x3 = ldatom(X,n,3);
  {
    float buf[16];
    rbf16(buf, dist_eps(x0, x1));
    #pragma unroll
    for (int t=0;t<16;++t) out[O_DISNODE + n*48 + t] = buf[t];
    rbf16(buf, dist_eps(x2, x1));
    #pragma unroll
    for (int t=0;t<16;++t) out[O_DISNODE + n*48 + 16 + t] = buf[t];
    rbf16(buf, dist_eps(x3, x1));
    #pragma unroll
    for (int t=0;t<16;++t) out[O_DISNODE + n*48 + 32 + t] = buf[t];
  }

  // ---- angle_node ----
  {
    const bool am = !((l <= 1) || ((l == LL-1) && (b < BB-1)));
    const float amf = am ? 1.f : 0.f;
    const int t0 = 3*n - 1;
    F3 P[6];
    #pragma unroll
    for (int q = 0; q < 6; ++q){
      int t = t0 + q;
      t = t < 0 ? 0 : (t > 3*NN - 1 ? 3*NN - 1 : t);
      const int nn2 = t / 3, aa = t - nn2*3;
      P[q] = ldatom(X, nn2, aa);
    }
    F3 U[5];
    #pragma unroll
    for (int q = 0; q < 5; ++q) U[q] = normf3(subf3(P[q+1], P[q]));
    #pragma unroll
    for (int cc = 0; cc < 3; ++cc){
      const int m = 3*n + cc - 1;
      float cD = 1.f, sD = 0.f, cA = 1.f, sA = 0.f;
      if (m >= 0 && m <= 3*NN - 4){
        const F3 u2 = U[cc], u1 = U[cc+1], u0 = U[cc+2];
        const F3 n2 = normf3(crossf3(u2, u1));
        const F3 n1 = normf3(crossf3(u1, u0));
        const float cd_ = clampf(dotf3(n2, n1), -1.f + EPSF, 1.f - EPSF);
        const float sg = sgnf(dotf3(u2, n1));
        cD = cd_;
        sD = sg * sqrtf(fmaxf(1.f - cd_*cd_, 0.f));
        const float ca_ = clampf(dotf3(u2, u1), -1.f + EPSF, 1.f - EPSF);
        cA = ca_;
        sA = sqrtf(fmaxf(1.f - ca_*ca_, 0.f));
      }
      out[O_ANGNODE + n*12 + cc]     = cD * amf;
      out[O_ANGNODE + n*12 + 3 + cc] = sD * amf;
      out[O_ANGNODE + n*12 + 6 + cc] = cA * amf;
      out[O_ANGNODE + n*12 + 9 + cc] = sA * amf;
    }
  }

  // ---- direct_node ---- (frames from ws)
  {
    const float4* W = (const float4*)ws;
    const float4 w0 = W[n*3+0], w1 = W[n*3+1], w2 = W[n*3+2];
    const F3 O0 = mkf3(w0.x,w0.y,w0.z), O1 = mkf3(w1.x,w1.y,w1.z), O2 = mkf3(w2.x,w2.y,w2.z);
    const F3 vs[3] = { subf3(x0, x1), subf3(x2, x1), subf3(x3, x1) };
    #pragma unroll
    for (int ai = 0; ai < 3; ++ai){
      F3 w = mkf3(dotf3(O0, vs[ai]), dotf3(O1, vs[ai]), dotf3(O2, vs[ai]));
      w = normf3(w);
      out[O_DIRNODE + n*9 + ai*3 + 0] = w.x;
      out[O_DIRNODE + n*9 + ai*3 + 1] = w.y;
      out[O_DIRNODE + n*9 + ai*3 + 2] = w.z;
    }
  }
}

// ================= kernel 3a: per-edge small outputs (LDS-staged coalesced writes) ====
__global__ __launch_bounds__(256) void edge_small_kernel(const float* __restrict__ X,
                                                         const int* __restrict__ seg,
                                                         const float* __restrict__ ws,
                                                         float* __restrict__ out){
  __shared__ float s_ctx[256], s_inter[256];
  __shared__ float s_ang[4][256];
  __shared__ float s_dir[9][256];
  const int tid = threadIdx.x;
  const int e0 = blockIdx.x * 256;
  const int e = e0 + tid;
  const int n = e / 9;
  const int c = (int)out[O_EIDX + NE + e];

  const float ctx = (seg[n] == seg[c]) ? 1.f : 0.f;
  s_ctx[tid] = ctx;
  s_inter[tid] = 1.f - ctx;

  const float4* W = (const float4*)ws;
  const float4 r0 = W[n*3+0], r1 = W[n*3+1], r2 = W[n*3+2];
  const float4 c0 = W[c*3+0], c1 = W[c*3+1], c2 = W[c*3+2];
  const F3 Ar0 = mkf3(r0.x,r0.y,r0.z), Ar1 = mkf3(r1.x,r1.y,r1.z), Ar2 = mkf3(r2.x,r2.y,r2.z);
  const F3 Ac0 = mkf3(c0.x,c0.y,c0.z), Ac1 = mkf3(c1.x,c1.y,c1.z), Ac2 = mkf3(c2.x,c2.y,c2.z);

  // angle_edge: quaternion of R = Or^T * Oc
  {
    const float R00 = Ar0.x*Ac0.x + Ar1.x*Ac1.x + Ar2.x*Ac2.x;
    const float R01 = Ar0.x*Ac0.y + Ar1.x*Ac1.y + Ar2.x*Ac2.y;
    const float R02 = Ar0.x*Ac0.z + Ar1.x*Ac1.z + Ar2.x*Ac2.z;
    const float R10 = Ar0.y*Ac0.x + Ar1.y*Ac1.x + Ar2.y*Ac2.x;
    const float R11 = Ar0.y*Ac0.y + Ar1.y*Ac1.y + Ar2.y*Ac2.y;
    const float R12 = Ar0.y*Ac0.z + Ar1.y*Ac1.z + Ar2.y*Ac2.z;
    const float R20 = Ar0.z*Ac0.x + Ar1.z*Ac1.x + Ar2.z*Ac2.x;
    const float R21 = Ar0.z*Ac0.y + Ar1.z*Ac1.y + Ar2.z*Ac2.y;
    const float R22 = Ar0.z*Ac0.z + Ar1.z*Ac1.z + Ar2.z*Ac2.z;
    const float m0 = 0.5f * sqrtf(fabsf(1.f + R00 - R11 - R22) + 1e-12f);
    const float m1 = 0.5f * sqrtf(fabsf(1.f - R00 + R11 - R22) + 1e-12f);
    const float m2 = 0.5f * sqrtf(fabsf(1.f - R00 - R11 + R22) + 1e-12f);
    const float qx = sgnf(R21 - R12) * m0;
    const float qy = sgnf(R02 - R20) * m1;
    const float qz = sgnf(R10 - R01) * m2;
    const float qw = sqrtf(fmaxf(1.f + R00 + R11 + R22, 0.f) + 1e-12f) * 0.5f;
    const float qn = fmaxf(sqrtf(qx*qx + qy*qy + qz*qz + qw*qw), 1e-12f);
    s_ang[0][tid] = qx / qn;
    s_ang[1][tid] = qy / qn;
    s_ang[2][tid] = qz / qn;
    s_ang[3][tid] = qw / qn;
  }

  // direct_edge: atoms {0,2,3} of row node, in col frame
  {
    const F3 xc1 = ldatom(X, c, 1);
    const int atoms[3] = {0, 2, 3};
    #pragma unroll
    for (int ai = 0; ai < 3; ++ai){
      const F3 xr = ldatom(X, n, atoms[ai]);
      const F3 vv = subf3(xr, xc1);
      F3 w = mkf3(dotf3(Ac0, vv), dotf3(Ac1, vv), dotf3(Ac2, vv));
      w = normf3(w);
      s_dir[ai*3+0][tid] = w.x;
      s_dir[ai*3+1][tid] = w.y;
      s_dir[ai*3+2][tid] = w.z;
    }
  }
  __syncthreads();

  out[O_CTX + e]   = s_ctx[tid];
  out[O_INTER + e] = s_inter[tid];
  #pragma unroll
  for (int i = 0; i < 4; ++i){
    const int f = tid + 256*i;
    out[O_ANGEDGE + e0*4 + f] = s_ang[f & 3][f >> 2];
  }
  #pragma unroll
  for (int i = 0; i < 9; ++i){
    const int f = tid + 256*i;
    out[O_DIREDGE + e0*9 + f] = s_dir[f % 9][f / 9];
  }
}

// ================= kernel 3b: edge_pos (thread == output element) =================
__global__ __launch_bounds__(256) void edge_pos_kernel(float* __restrict__ out){
  const int gid = blockIdx.x * 256 + threadIdx.x;   // < NE*16
  const int e = gid >> 4, t = gid & 15;
  const int n = e / 9;
  const int c = (int)out[O_EIDX + NE + e];
  const float p = (float)(n - c);
  float sv, cv;
  sincosf(p * frq_dyn(t & 7), &sv, &cv);
  out[O_EDGEPOS + gid] = (t < 8) ? cv : sv;
}

// ================= kernel 3c: dis_edge (thread == output element) =================
__global__ __launch_bounds__(256) void dis_edge_kernel(const float* __restrict__ X,
                                                       float* __restrict__ out){
  const int gid = blockIdx.x * 256 + threadIdx.x;   // < NE*64
  const int e = gid >> 6, t = gid & 63;
  const int a = t >> 4, ch = t & 15;
  const int n = e / 9;
  const int c = (int)out[O_EIDX + NE + e];
  const F3 xr = ldatom(X, n, a);
  const F3 xc = ldatom(X, c, 1);
  const float d = dist_eps(xr, xc);
  const float mu = (float)ch * (20.0f/15.0f);
  const float z = (d - mu) * (1.0f/1.25f);
  out[O_DISEDGE + gid] = __expf(-z*z);
}

extern "C" void kernel_launch(void* const* d_in, const int* in_sizes, int n_in,
                              void* d_out, int out_size, void* d_ws, size_t ws_size,
                              hipStream_t stream) {
  const float* X = (const float*)d_in[0];
  const int* seg = (const int*)d_in[1];
  float* out = (float*)d_out;
  float* ws = (float*)d_ws;   // 32768*12 floats = 1.57 MB of O-frames
  topk_kernel<<<NN/32, 256, 0, stream>>>(X, out);
  frames_kernel<<<NN/256, 256, 0, stream>>>(X, ws);
  node_kernel<<<NN/256, 256, 0, stream>>>(X, ws, out);
  edge_small_kernel<<<NE/256, 256, 0, stream>>>(X, seg, ws, out);
  edge_pos_kernel<<<(NE*16)/256, 256, 0, stream>>>(out);
  dis_edge_kernel<<<(NE*64)/256, 256, 0, stream>>>(X, out);
}

// Round 3
// 224.611 us; speedup vs baseline: 1.2771x; 1.2080x over previous
//
#include <hip/hip_runtime.h>
#include <math.h>

#define NN 32768
#define BB 16
#define LL 2048
#define NE (NN*9)
#define EPSF 1e-6f
#define CAP 32

// ---- output layout (flat float32, reference tuple order) ----
#define O_NODEPOS 0
#define O_DISNODE (NN*16)
#define O_ANGNODE (O_DISNODE + NN*48)
#define O_DIRNODE (O_ANGNODE + NN*12)
#define O_EIDX    (O_DIRNODE + NN*9)
#define O_CTX     (O_EIDX + 2*NE)
#define O_INTER   (O_CTX + NE)
#define O_EDGEPOS (O_INTER + NE)
#define O_DISEDGE (O_EDGEPOS + NE*16)
#define O_ANGEDGE (O_DISEDGE + NE*64)
#define O_DIREDGE (O_ANGEDGE + NE*4)

struct F3 { float x, y, z; };
__device__ __forceinline__ F3 mkf3(float x, float y, float z){ F3 r; r.x=x; r.y=y; r.z=z; return r; }
__device__ __forceinline__ F3 subf3(F3 a, F3 b){ return mkf3(a.x-b.x, a.y-b.y, a.z-b.z); }
__device__ __forceinline__ float dotf3(F3 a, F3 b){ return a.x*b.x + a.y*b.y + a.z*b.z; }
__device__ __forceinline__ F3 crossf3(F3 a, F3 b){
  return mkf3(a.y*b.z - a.z*b.y, a.z*b.x - a.x*b.z, a.x*b.y - a.y*b.x);
}
__device__ __forceinline__ F3 normf3(F3 v){
  float n = sqrtf(v.x*v.x + v.y*v.y + v.z*v.z);
  float m = fmaxf(n, 1e-12f);
  return mkf3(v.x/m, v.y/m, v.z/m);
}
__device__ __forceinline__ float sgnf(float x){ return (x > 0.f) ? 1.f : ((x < 0.f) ? -1.f : 0.f); }
__device__ __forceinline__ float clampf(float x, float lo, float hi){ return fminf(fmaxf(x, lo), hi); }

__device__ __forceinline__ F3 ldatom(const float* __restrict__ X, int n, int a){
  const float* p = X + (size_t)n*12 + a*3;
  return mkf3(p[0], p[1], p[2]);
}
__device__ __forceinline__ float dist_eps(F3 a, F3 b){
  F3 d = subf3(a, b);
  return sqrtf(dotf3(d, d) + EPSF);
}
// freq[t] = 10000^(-t/8), t=0..7
__device__ __forceinline__ float frq(int t){
  const float F[8] = {1.0f, 0.31622776601683794f, 0.1f, 0.031622776601683794f,
                      0.01f, 0.0031622776601683794f, 0.001f, 0.00031622776601683794f};
  return F[t];
}
__device__ __forceinline__ float frq_dyn(int t){
  return exp2f((float)t * -1.6609640474436813f);
}
__device__ __forceinline__ void rbf16(float* __restrict__ dst, float d){
  #pragma unroll
  for (int t = 0; t < 16; ++t){
    float mu = (float)t * (20.0f/15.0f);
    float z = (d - mu) * (1.0f/1.25f);
    dst[t] = __expf(-z*z);
  }
}
// O frame for node n (zero if padded/masked). Rows O0,O1,O2 = o1, nf, o1 x nf.
__device__ __forceinline__ void computeO(const float* __restrict__ X, int n, F3& O0, F3& O1, F3& O2){
  int l = n & (LL-1);
  int b = n >> 11;
  bool fm = !((l <= 1) || ((l >= LL-2) && (b < BB-1)));
  bool has = fm && (n >= 1) && (n <= NN-3);
  if (has){
    F3 cm = ldatom(X, n-1, 1), c0 = ldatom(X, n, 1), cp = ldatom(X, n+1, 1);
    F3 uc2 = normf3(subf3(c0, cm));
    F3 uc1 = normf3(subf3(cp, c0));
    F3 nf  = normf3(crossf3(uc2, uc1));
    F3 o1  = normf3(subf3(uc2, uc1));
    O0 = o1; O1 = nf; O2 = crossf3(o1, nf);
  } else {
    O0 = mkf3(0,0,0); O1 = mkf3(0,0,0); O2 = mkf3(0,0,0);
  }
}

// ================= kernel 1: per-batch top-9 nearest neighbors =================
// Pass 1: per-lane top-3 VALUES only (6 min/max per candidate). The merged 9th
// smallest of the 8x3 kept values is provably >= true s9 (at most 8 global
// values lie strictly below s9), so it is a valid rescan threshold.
// Pass 2: rescan with the bit-identical distance; exact (s,idx)-lex top-9.
__global__ __launch_bounds__(512, 6) void topk_kernel(const float* __restrict__ X,
                                                      float* __restrict__ out){
  __shared__ float4 sca[LL + (LL >> 8)];           // skewed stage of batch CA coords
  __shared__ unsigned long long ebuf[64][CAP];
  __shared__ int ecnt[64];
  const int tid = threadIdx.x;
  const int block0 = blockIdx.x * 64;              // 64 rows per block
  const int base = (block0 >> 11) << 11;

  if (tid < 64) ecnt[tid] = 0;
  for (int p = tid; p < LL; p += 512){
    const float* xp = X + (size_t)(base + p)*12 + 3;   // CA atom
    sca[p + (p >> 8)] = make_float4(xp[0], xp[1], xp[2], 0.f);
  }
  __syncthreads();

  const int r = tid >> 3;          // row within block (0..63)
  const int k = tid & 7;           // lane group within row
  const int n = block0 + r;
  const int il = n - base;
  const float4 ci = sca[il + (il >> 8)];
  const float4* __restrict__ basep = &sca[(k << 8) + k];  // lane's 256 contiguous float4s

  float v0 = __builtin_inff(), v1 = __builtin_inff(), v2 = __builtin_inff();

  #pragma unroll 8
  for (int jj = 0; jj < 256; ++jj){
    const float4 cj = basep[jj];
    const float dx = ci.x - cj.x, dy = ci.y - cj.y, dz = ci.z - cj.z;
    float key = fmaf(dz, dz, fmaf(dy, dy, dx*dx));
    float mn;
    mn = fminf(key, v0); key = fmaxf(key, v0); v0 = mn;
    mn = fminf(key, v1); key = fmaxf(key, v1); v1 = mn;
    mn = fminf(key, v2); key = fmaxf(key, v2); v2 = mn;
  }

  // 9 pop-rounds over the 8 sorted 3-lists -> t9 >= true 9th smallest
  float t9 = 0.f;
  #pragma unroll
  for (int t = 0; t < 9; ++t){
    const float h = v0;
    float m = h;
    m = fminf(m, __shfl_xor(m, 1, 8));
    m = fminf(m, __shfl_xor(m, 2, 8));
    m = fminf(m, __shfl_xor(m, 4, 8));
    const bool pop = (h == m);
    v0 = pop ? v1 : v0;
    v1 = pop ? v2 : v1;
    v2 = pop ? __builtin_inff() : v2;
    t9 = m;
  }

  // rescan: exact (s,idx) for everything at or below the threshold
  #pragma unroll 4
  for (int jj = 0; jj < 256; ++jj){
    const float4 cj = basep[jj];
    const float dx = ci.x - cj.x, dy = ci.y - cj.y, dz = ci.z - cj.z;
    const float s = fmaf(dz, dz, fmaf(dy, dy, dx*dx));   // bit-identical to pass 1
    if (s <= t9){
      const int slot = atomicAdd(&ecnt[r], 1);
      if (slot < CAP)
        ebuf[r][slot] = ((unsigned long long)__float_as_uint(s) << 32) | (unsigned)((k << 8) + jj);
    }
  }
  __syncthreads();

  if (k == 0){
    const int m = min(ecnt[r], CAP);
    unsigned long long kk[9];
    #pragma unroll
    for (int t = 0; t < 9; ++t) kk[t] = ~0ull;
    for (int j = 0; j < m; ++j){
      unsigned long long key = ebuf[r][j];
      #pragma unroll
      for (int t = 0; t < 9; ++t){
        const bool lt = key < kk[t];
        const unsigned long long mn = lt ? key : kk[t];
        const unsigned long long mx = lt ? kk[t] : key;
        kk[t] = mn; key = mx;
      }
    }
    const int be = n * 9;
    #pragma unroll
    for (int t = 0; t < 9; ++t){
      out[O_EIDX + be + t] = (float)n;
      out[O_EIDX + NE + be + t] = (float)(base + (int)(unsigned)kk[t]);
    }
  }
}

// ================= kernel 2: node features + O-frames to ws =================
__global__ __launch_bounds__(256) void node_kernel(const float* __restrict__ X,
                                                   float* __restrict__ ws,
                                                   float* __restrict__ out){
  const int n = blockIdx.x * 256 + threadIdx.x;
  if (n >= NN) return;
  const int l = n & (LL-1);
  const int b = n >> 11;

  // ---- O frame (also used by direct_node below) ----
  F3 O0, O1, O2;
  computeO(X, n, O0, O1, O2);
  {
    float4* W = (float4*)ws;
    W[n*3 + 0] = make_float4(O0.x, O0.y, O0.z, 0.f);
    W[n*3 + 1] = make_float4(O1.x, O1.y, O1.z, 0.f);
    W[n*3 + 2] = make_float4(O2.x, O2.y, O2.z, 0.f);
  }

  // ---- node_pos ----
  {
    const float p = (float)l;
    #pragma unroll
    for (int t = 0; t < 8; ++t){
      float sv, cv;
      __sincosf(p * frq(t), &sv, &cv);
      out[O_NODEPOS + n*16 + t] = cv;
      out[O_NODEPOS + n*16 + 8 + t] = sv;
    }
  }

  // ---- dis_node ----
  const F3 x0 = ldatom(X,n,0), x1 = ldatom(X,n,1), x2 = ldatom(X,n,2), x3 = ldatom(X,n,3);
  {
    float buf[16];
    rbf16(buf, dist_eps(x0, x1));
    #pragma unroll
    for (int t=0;t<16;++t) out[O_DISNODE + n*48 + t] = buf[t];
    rbf16(buf, dist_eps(x2, x1));
    #pragma unroll
    for (int t=0;t<16;++t) out[O_DISNODE + n*48 + 16 + t] = buf[t];
    rbf16(buf, dist_eps(x3, x1));
    #pragma unroll
    for (int t=0;t<16;++t) out[O_DISNODE + n*48 + 32 + t] = buf[t];
  }

  // ---- angle_node ----
  {
    const bool am = !((l <= 1) || ((l == LL-1) && (b < BB-1)));
    const float amf = am ? 1.f : 0.f;
    const int t0 = 3*n - 1;
    F3 P[6];
    #pragma unroll
    for (int q = 0; q < 6; ++q){
      int t = t0 + q;
      t = t < 0 ? 0 : (t > 3*NN - 1 ? 3*NN - 1 : t);
      const int nn2 = t / 3, aa = t - nn2*3;
      P[q] = ldatom(X, nn2, aa);
    }
    F3 U[5];
    #pragma unroll
    for (int q = 0; q < 5; ++q) U[q] = normf3(subf3(P[q+1], P[q]));
    #pragma unroll
    for (int cc = 0; cc < 3; ++cc){
      const int m = 3*n + cc - 1;
      float cD = 1.f, sD = 0.f, cA = 1.f, sA = 0.f;
      if (m >= 0 && m <= 3*NN - 4){
        const F3 u2 = U[cc], u1 = U[cc+1], u0 = U[cc+2];
        const F3 n2 = normf3(crossf3(u2, u1));
        const F3 n1 = normf3(crossf3(u1, u0));
        const float cd_ = clampf(dotf3(n2, n1), -1.f + EPSF, 1.f - EPSF);
        const float sg = sgnf(dotf3(u2, n1));
        cD = cd_;
        sD = sg * sqrtf(fmaxf(1.f - cd_*cd_, 0.f));
        const float ca_ = clampf(dotf3(u2, u1), -1.f + EPSF, 1.f - EPSF);
        cA = ca_;
        sA = sqrtf(fmaxf(1.f - ca_*ca_, 0.f));
      }
      out[O_ANGNODE + n*12 + cc]     = cD * amf;
      out[O_ANGNODE + n*12 + 3 + cc] = sD * amf;
      out[O_ANGNODE + n*12 + 6 + cc] = cA * amf;
      out[O_ANGNODE + n*12 + 9 + cc] = sA * amf;
    }
  }

  // ---- direct_node ----
  {
    const F3 vs[3] = { subf3(x0, x1), subf3(x2, x1), subf3(x3, x1) };
    #pragma unroll
    for (int ai = 0; ai < 3; ++ai){
      F3 w = mkf3(dotf3(O0, vs[ai]), dotf3(O1, vs[ai]), dotf3(O2, vs[ai]));
      w = normf3(w);
      out[O_DIRNODE + n*9 + ai*3 + 0] = w.x;
      out[O_DIRNODE + n*9 + ai*3 + 1] = w.y;
      out[O_DIRNODE + n*9 + ai*3 + 2] = w.z;
    }
  }
}

// ==== kernel 3: ctx/inter + angle_edge + direct_edge + edge_pos (coalesced) ====
__global__ __launch_bounds__(256) void edge_small_kernel(const float* __restrict__ X,
                                                         const int* __restrict__ seg,
                                                         const float* __restrict__ ws,
                                                         float* __restrict__ out){
  __shared__ float s_ang[4][257];
  __shared__ float s_dir[9][257];
  __shared__ float s_pos[16][257];
  const int tid = threadIdx.x;
  const int e0 = blockIdx.x * 256;
  const int e = e0 + tid;
  const int n = e / 9;
  const int c = (int)out[O_EIDX + NE + e];

  const float ctx = (seg[n] == seg[c]) ? 1.f : 0.f;

  // edge_pos staging
  {
    const float p = (float)(n - c);
    #pragma unroll
    for (int t = 0; t < 8; ++t){
      float sv, cv;
      __sincosf(p * frq(t), &sv, &cv);
      s_pos[t][tid] = cv;
      s_pos[8 + t][tid] = sv;
    }
  }

  const float4* W = (const float4*)ws;
  const float4 r0 = W[n*3+0], r1 = W[n*3+1], r2 = W[n*3+2];
  const float4 c0 = W[c*3+0], c1 = W[c*3+1], c2 = W[c*3+2];
  const F3 Ar0 = mkf3(r0.x,r0.y,r0.z), Ar1 = mkf3(r1.x,r1.y,r1.z), Ar2 = mkf3(r2.x,r2.y,r2.z);
  const F3 Ac0 = mkf3(c0.x,c0.y,c0.z), Ac1 = mkf3(c1.x,c1.y,c1.z), Ac2 = mkf3(c2.x,c2.y,c2.z);

  // angle_edge: quaternion of R = Or^T * Oc
  {
    const float R00 = Ar0.x*Ac0.x + Ar1.x*Ac1.x + Ar2.x*Ac2.x;
    const float R01 = Ar0.x*Ac0.y + Ar1.x*Ac1.y + Ar2.x*Ac2.y;
    const float R02 = Ar0.x*Ac0.z + Ar1.x*Ac1.z + Ar2.x*Ac2.z;
    const float R10 = Ar0.y*Ac0.x + Ar1.y*Ac1.x + Ar2.y*Ac2.x;
    const float R11 = Ar0.y*Ac0.y + Ar1.y*Ac1.y + Ar2.y*Ac2.y;
    const float R12 = Ar0.y*Ac0.z + Ar1.y*Ac1.z + Ar2.y*Ac2.z;
    const float R20 = Ar0.z*Ac0.x + Ar1.z*Ac1.x + Ar2.z*Ac2.x;
    const float R21 = Ar0.z*Ac0.y + Ar1.z*Ac1.y + Ar2.z*Ac2.y;
    const float R22 = Ar0.z*Ac0.z + Ar1.z*Ac1.z + Ar2.z*Ac2.z;
    const float m0 = 0.5f * sqrtf(fabsf(1.f + R00 - R11 - R22) + 1e-12f);
    const float m1 = 0.5f * sqrtf(fabsf(1.f - R00 + R11 - R22) + 1e-12f);
    const float m2 = 0.5f * sqrtf(fabsf(1.f - R00 - R11 + R22) + 1e-12f);
    const float qx = sgnf(R21 - R12) * m0;
    const float qy = sgnf(R02 - R20) * m1;
    const float qz = sgnf(R10 - R01) * m2;
    const float qw = sqrtf(fmaxf(1.f + R00 + R11 + R22, 0.f) + 1e-12f) * 0.5f;
    const float qn = fmaxf(sqrtf(qx*qx + qy*qy + qz*qz + qw*qw), 1e-12f);
    s_ang[0][tid] = qx / qn;
    s_ang[1][tid] = qy / qn;
    s_ang[2][tid] = qz / qn;
    s_ang[3][tid] = qw / qn;
  }

  // direct_edge: atoms {0,2,3} of row node, in col frame
  {
    const F3 xc1 = ldatom(X, c, 1);
    const int atoms[3] = {0, 2, 3};
    #pragma unroll
    for (int ai = 0; ai < 3; ++ai){
      const F3 xr = ldatom(X, n, atoms[ai]);
      const F3 vv = subf3(xr, xc1);
      F3 w = mkf3(dotf3(Ac0, vv), dotf3(Ac1, vv), dotf3(Ac2, vv));
      w = normf3(w);
      s_dir[ai*3+0][tid] = w.x;
      s_dir[ai*3+1][tid] = w.y;
      s_dir[ai*3+2][tid] = w.z;
    }
  }
  __syncthreads();

  out[O_CTX + e]   = ctx;
  out[O_INTER + e] = 1.f - ctx;
  #pragma unroll
  for (int i = 0; i < 4; ++i){
    const int f = tid + 256*i;
    out[O_ANGEDGE + e0*4 + f] = s_ang[f & 3][f >> 2];
  }
  #pragma unroll
  for (int i = 0; i < 9; ++i){
    const int f = tid + 256*i;
    out[O_DIREDGE + e0*9 + f] = s_dir[f % 9][f / 9];
  }
  #pragma unroll
  for (int i = 0; i < 16; ++i){
    const int f = tid + 256*i;
    out[O_EDGEPOS + e0*16 + f] = s_pos[f & 15][f >> 4];
  }
}

// ================= kernel 4: dis_edge (thread == output element) =================
__global__ __launch_bounds__(256) void dis_edge_kernel(const float* __restrict__ X,
                                                       float* __restrict__ out){
  const int gid = blockIdx.x * 256 + threadIdx.x;   // < NE*64
  const int e = gid >> 6, t = gid & 63;
  const int a = t >> 4, ch = t & 15;
  const int n = e / 9;
  const int c = (int)out[O_EIDX + NE + e];
  const F3 xr = ldatom(X, n, a);
  const F3 xc = ldatom(X, c, 1);
  const float d = dist_eps(xr, xc);
  const float mu = (float)ch * (20.0f/15.0f);
  const float z = (d - mu) * (1.0f/1.25f);
  out[O_DISEDGE + gid] = __expf(-z*z);
}

extern "C" void kernel_launch(void* const* d_in, const int* in_sizes, int n_in,
                              void* d_out, int out_size, void* d_ws, size_t ws_size,
                              hipStream_t stream) {
  const float* X = (const float*)d_in[0];
  const int* seg = (const int*)d_in[1];
  float* out = (float*)d_out;
  float* ws = (float*)d_ws;   // 32768*12 floats = 1.57 MB of O-frames
  topk_kernel<<<NN/64, 512, 0, stream>>>(X, out);          // edge_index
  node_kernel<<<NN/256, 256, 0, stream>>>(X, ws, out);     // node features + frames
  edge_small_kernel<<<NE/256, 256, 0, stream>>>(X, seg, ws, out);
  dis_edge_kernel<<<(NE*64)/256, 256, 0, stream>>>(X, out);
}